// Round 13
// baseline (328.260 us; speedup 1.0000x reference)
//
#include <hip/hip_runtime.h>
#include <hip/hip_bf16.h>
#include <math.h>

#define NH 16
#define NKV 4
#define HD 128
#define SEQ 2048
#define BATCH 2
#define EPSF 1e-6f
#define QKV 3072      // fused projection width: 2048 q | 512 k | 512 v

typedef __attribute__((ext_vector_type(8))) short bf16x8;
typedef __attribute__((ext_vector_type(4))) short short4v;
typedef __attribute__((ext_vector_type(4))) float f32x4;

__device__ __forceinline__ short f2bf(float x) {
    unsigned u = __float_as_uint(x);
    u += 0x7fffu + ((u >> 16) & 1u);      // round-to-nearest-even
    return (short)(u >> 16);
}
__device__ __forceinline__ float bf2f(short x) {
    return __uint_as_float((unsigned)(unsigned short)x << 16);
}
// packed f32x2 -> bf16x2 (v_cvt_pk_bf16_f32), RNE
__device__ __forceinline__ unsigned pkbf(float a, float b) {
    __hip_bfloat162 h = __float22bfloat162_rn(float2{a, b});
    unsigned r; __builtin_memcpy(&r, &h, 4); return r;
}

// async global->LDS, 16B per lane; LDS dest = wave-uniform base + lane*16
__device__ __forceinline__ void gll16(const short* g, short* l) {
    __builtin_amdgcn_global_load_lds(
        (const __attribute__((address_space(1))) unsigned*)g,
        (__attribute__((address_space(3))) unsigned*)l, 16, 0, 0);
}

// ---------------------------------------------------------------------------
// Fused fp32->bf16 casts + RoPE cos/sin table build.
// blocks [0,8192): hs, [8192,12288): Wq, [12288,13312): Wk,
// [13312,14336): Wv, [14336,18432): Wo, [18432,18944): rope table.
// ---------------------------------------------------------------------------
__global__ __launch_bounds__(256)
void cast_all(const float* __restrict__ hs, const float* __restrict__ Wq,
              const float* __restrict__ Wk, const float* __restrict__ Wv,
              const float* __restrict__ Wo, short* __restrict__ hsb,
              short* __restrict__ wqkv, short* __restrict__ wob,
              float2* __restrict__ rtab)
{
    const size_t MEG = 1024 * 1024;
    const int id = blockIdx.x;
    if (id >= 18432) {
        // rope table: rtab[s*64+j] = {cos, sin} of s * 10000^(-j/64)
        const int idx = (id - 18432) * 256 + threadIdx.x;   // 0..131071
        const int s = idx >> 6, j = idx & 63;
        const float inv_freq = exp2f(-(float)j * (13.287712379549449f / 64.0f));
        const float ang = (float)s * inv_freq;
        float sn, c;
        __sincosf(ang, &sn, &c);
        rtab[idx] = float2{c, sn};
        return;
    }
    const float* s;
    short* d;
    size_t off;
    if (id < 8192)       { s = hs; d = hsb;            off = (size_t)id * 1024; }
    else if (id < 12288) { s = Wq; d = wqkv;           off = (size_t)(id - 8192) * 1024; }
    else if (id < 13312) { s = Wk; d = wqkv + 4 * MEG; off = (size_t)(id - 12288) * 1024; }
    else if (id < 14336) { s = Wv; d = wqkv + 5 * MEG; off = (size_t)(id - 13312) * 1024; }
    else                 { s = Wo; d = wob;            off = (size_t)(id - 14336) * 1024; }
    const size_t i = off + threadIdx.x * 4;
    float4 v = *(const float4*)(s + i);
    short4v o;
    o.x = f2bf(v.x); o.y = f2bf(v.y); o.z = f2bf(v.z); o.w = f2bf(v.w);
    *(short4v*)(d + i) = o;
}

// ---------------------------------------------------------------------------
// bf16 MFMA GEMM NT (measured-best config, FINAL): 128x128 tile, BK=64,
// XOR-swizzled LDS (gll16-compatible), XCD-aware remap (n-fast walk),
// 256 threads, LB(256,4). C[M,N] = A[M,K] @ B[N,K]^T, fp32 accum.
// Measured notes: n-fast beats m-fast (R11 +15us regression); LB(256,4)
// beats (256,3); 256x256 8-phase loses at these grid sizes (R3/R4 +35us).
// ---------------------------------------------------------------------------
template<bool OUT_BF16>
__global__ __launch_bounds__(256, 4)
void gemm_nt_mfma(const short* __restrict__ A, const short* __restrict__ B,
                  void* __restrict__ Cv, int N, int K, int gridX, int total)
{
    __shared__ short As[128 * 64];
    __shared__ short Bs[128 * 64];

    const int tid = threadIdx.x;
    const int w = tid >> 6, lane = tid & 63;
    const int quad = lane >> 4, ln = lane & 15;
    const int mw = (w >> 1) * 64, nw = (w & 1) * 64;

    // XCD-aware remap: XCD (id&7) walks a contiguous chunk of tiles
    const int id = blockIdx.x;
    const int t = (id & 7) * (total >> 3) + (id >> 3);
    const int n0 = (t % gridX) * 128;
    const int m0 = (t / gridX) * 128;

    // staging: wave w, round r covers rows w*8 + 32r + (lane>>3),
    // lane fetches swizzled source granule ((lane&7) ^ (lane>>3))
    const int rr = lane >> 3;
    const int gsw = ((lane & 7) ^ rr) * 8;
    const short* Ag[4]; const short* Bg[4];
    short* Al[4]; short* Bl[4];
    #pragma unroll
    for (int r = 0; r < 4; ++r) {
        const int row = w * 8 + 32 * r + rr;
        Ag[r] = A + (size_t)(m0 + row) * K + gsw;
        Bg[r] = B + (size_t)(n0 + row) * K + gsw;
        Al[r] = &As[(w * 8 + 32 * r) * 64];
        Bl[r] = &Bs[(w * 8 + 32 * r) * 64];
    }

    // read column offsets (shorts) for substeps ks=0,1: ((ks*4+quad)^(ln&7))*8
    const int col0 = ((quad) ^ (ln & 7)) * 8;
    const int col1 = ((4 + quad) ^ (ln & 7)) * 8;

    f32x4 acc[4][4];
    #pragma unroll
    for (int i = 0; i < 4; ++i)
        #pragma unroll
        for (int j = 0; j < 4; ++j)
            acc[i][j] = (f32x4){0.f, 0.f, 0.f, 0.f};

    for (int k0 = 0; k0 < K; k0 += 64) {
        __syncthreads();
        #pragma unroll
        for (int r = 0; r < 4; ++r) {
            gll16(Ag[r] + k0, Al[r]);
            gll16(Bg[r] + k0, Bl[r]);
        }
        __syncthreads();   // drains vmcnt -> LDS populated

        #pragma unroll
        for (int ks = 0; ks < 2; ++ks) {
            const int col = ks ? col1 : col0;
            bf16x8 af[4], bfr[4];
            #pragma unroll
            for (int i = 0; i < 4; ++i)
                af[i] = *(const bf16x8*)&As[(mw + i * 16 + ln) * 64 + col];
            #pragma unroll
            for (int j = 0; j < 4; ++j)
                bfr[j] = *(const bf16x8*)&Bs[(nw + j * 16 + ln) * 64 + col];
            #pragma unroll
            for (int i = 0; i < 4; ++i)
                #pragma unroll
                for (int j = 0; j < 4; ++j)
                    acc[i][j] = __builtin_amdgcn_mfma_f32_16x16x32_bf16(
                        af[i], bfr[j], acc[i][j], 0, 0, 0);
        }
    }

    #pragma unroll
    for (int i = 0; i < 4; ++i) {
        #pragma unroll
        for (int reg = 0; reg < 4; ++reg) {
            const int row = m0 + mw + i * 16 + quad * 4 + reg;
            const size_t base = (size_t)row * N + n0 + nw;
            #pragma unroll
            for (int j = 0; j < 4; ++j) {
                if (OUT_BF16)
                    ((short*)Cv)[base + j * 16 + ln] = f2bf(acc[i][j][reg]);
                else
                    ((float*)Cv)[base + j * 16 + ln] = acc[i][j][reg];
            }
        }
    }
}

// ---------------------------------------------------------------------------
// Fused: RMSNorm+RoPE on q|k (blocks [0,20480)) AND V-transpose
// (blocks [20480,22528)). RoPE cos/sin from precomputed table.
// ---------------------------------------------------------------------------
#define NR_BLOCKS 20480    // (BATCH*SEQ*(NH+NKV))/4
__global__ __launch_bounds__(256)
void norm_rope_tv(short* __restrict__ qkv, const float* __restrict__ qw,
                  const float* __restrict__ kw, short* __restrict__ vT,
                  const float2* __restrict__ rtab)
{
    if (blockIdx.x < NR_BLOCKS) {
        // ---- RMSNorm + RoPE ----
        const int wave = threadIdx.x >> 6;
        const int lane = threadIdx.x & 63;
        const long vec = (long)blockIdx.x * 4 + wave;
        const long NQ = (long)BATCH * SEQ * NH;

        short* base;
        const float* w;
        int s;
        if (vec < NQ) {
            const long token = vec / NH;
            const int h = (int)(vec % NH);
            s = (int)(token % SEQ);
            base = qkv + token * QKV + h * HD;
            w = qw;
        } else {
            const long t = vec - NQ;
            const long token = t / NKV;
            const int kvh = (int)(t % NKV);
            s = (int)(token % SEQ);
            base = qkv + token * QKV + 2048 + kvh * HD;
            w = kw;
        }

        float x0 = bf2f(base[lane]);
        float x1 = bf2f(base[lane + 64]);
        float ss = x0 * x0 + x1 * x1;
        #pragma unroll
        for (int off = 32; off; off >>= 1) ss += __shfl_xor(ss, off, 64);
        const float r = rsqrtf(ss * (1.0f / HD) + EPSF);
        x0 = x0 * r * w[lane];
        x1 = x1 * r * w[lane + 64];

        const float2 cs = rtab[(size_t)s * 64 + lane];
        base[lane]      = f2bf(x0 * cs.x - x1 * cs.y);
        base[lane + 64] = f2bf(x1 * cs.x + x0 * cs.y);
    } else {
        // ---- V transpose: qkv[token][2560+kvh*128+d] -> vT[b][kvh][d][s] ----
        __shared__ short T[32][33];
        const int bx = blockIdx.x - NR_BLOCKS;
        const int st = bx & 63;
        const int dt = (bx >> 6) & 3;
        const int bk = bx >> 8;
        const int s0 = st * 32, d0 = dt * 32;
        const int tid = threadIdx.x;
        const long tok0 = (long)(bk >> 2) * SEQ + s0;
        const int kvh = bk & 3;

        const int rs = tid >> 3;
        const int rc = (tid & 7) * 4;
        short4v val = *(const short4v*)(qkv + (tok0 + rs) * QKV + 2560 + kvh * HD + d0 + rc);
        T[rc + 0][rs] = val.x; T[rc + 1][rs] = val.y;
        T[rc + 2][rs] = val.z; T[rc + 3][rs] = val.w;
        __syncthreads();

        const int wd = tid >> 3;
        const int wsc = (tid & 7) * 4;
        short4v ov;
        ov.x = T[wd][wsc + 0]; ov.y = T[wd][wsc + 1];
        ov.z = T[wd][wsc + 2]; ov.w = T[wd][wsc + 3];
        *(short4v*)(vT + ((size_t)bk * HD + d0 + wd) * SEQ + s0 + wsc) = ov;
    }
}

// ---------------------------------------------------------------------------
// Flash causal GQA attention v4 (measured-best config, FINAL): 8 waves,
// paired complementary (qa=pair, qb=31-pair) q-groups sharing K/V staging.
// bf16 MFMA, fp32 accum. T2 XOR swizzle on Ks/Vt/Ps, T5 setprio,
// T13 defer-max. Six schedule experiments confirm this is the optimum of
// this structure family.
// ---------------------------------------------------------------------------
__global__ __launch_bounds__(512, 4)
void flash_attn_mfma(const short* __restrict__ qkv, const short* __restrict__ vT,
                     short* __restrict__ o)
{
    __shared__ short Ks[64 * 128];     // [key][d], 16 granules/row, XOR-swizzled
    __shared__ short Vt[128 * 64];     // [d][key], 8 granules/row, XOR-swizzled
    __shared__ short Ps[8][16 * 64];   // per-wave [q][key], XOR-swizzled

    const int tid = threadIdx.x;
    const int w = tid >> 6;            // 0..7
    const int lane = tid & 63;
    const int quad = lane >> 4;
    const int ln = lane & 15;
    const int lnm = ln & 7;
    const int side = w >> 2;           // 0 -> qa, 1 -> qb
    const int sw = w & 3;

    const int bx = blockIdx.x;
    const int pair = bx & 15;
    const int bh = bx >> 4;
    const int h = bh & 15;
    const int b = bh >> 4;
    const int kvh = h >> 2;
    const int qa = pair, qb = 31 - pair;
    const int qX = side ? qb : qa;
    const int rX = qX * 64 + sw * 16;

    const float SC = 0.08838834764831845f * 1.4426950408889634f; // 1/sqrt(HD)*log2e

    // swizzled read column offsets (shorts): logical granule ^ (row&7 == ln&7)
    int colK[4];
    #pragma unroll
    for (int f = 0; f < 4; ++f) {
        const int lg = f * 4 + quad;                    // logical granule 0..15
        colK[f] = ((lg & 8) | ((lg ^ lnm) & 7)) * 8;
    }
    const int colA = (quad ^ lnm) * 8;                  // logical granule quad
    const int colB = ((4 + quad) ^ lnm) * 8;            // logical granule 4+quad

    // Q -> B-frags (lane ln = q row rX+ln)
    bf16x8 qf[4];
    {
        const short* qrow = qkv + (size_t)(b * SEQ + rX + ln) * QKV + h * HD;
        #pragma unroll
        for (int f = 0; f < 4; ++f)
            qf[f] = *(const bf16x8*)(qrow + f * 32 + quad * 8);
    }

    f32x4 Oa[8];
    #pragma unroll
    for (int dg = 0; dg < 8; ++dg) Oa[dg] = (f32x4){0.f, 0.f, 0.f, 0.f};
    float mX = -1e30f, lX = 0.f;

    const short* kbase = qkv + (size_t)(b * SEQ) * QKV + 2048 + kvh * HD;
    const short* vbase = vT + (size_t)(b * NKV + kvh) * HD * SEQ;

    bf16x8 kp[2], vp[2];
    auto prefetch = [&](int k0) {
        #pragma unroll
        for (int i = 0; i < 2; ++i) {
            const int e = tid + i * 512;
            kp[i] = *(const bf16x8*)(kbase + (size_t)(k0 + (e >> 4)) * QKV + (e & 15) * 8);
            vp[i] = *(const bf16x8*)(vbase + (size_t)(e >> 3) * SEQ + k0 + (e & 7) * 8);
        }
    };
    prefetch(0);

    for (int kt = 0; kt <= qb; ++kt) {
        const int k0 = kt * 64;
        __syncthreads();
        #pragma unroll
        for (int i = 0; i < 2; ++i) {
            const int e = tid + i * 512;
            const int kr = e >> 4, kg = e & 15;
            *(bf16x8*)&Ks[kr * 128 + ((kg & 8) | ((kg ^ (kr & 7)) & 7)) * 8] = kp[i];
            const int vd = e >> 3, vg = e & 7;
            *(bf16x8*)&Vt[vd * 64 + ((vg ^ (vd & 7)) * 8)] = vp[i];
        }
        __syncthreads();
        if (kt < qb) prefetch(k0 + 64);

        if (kt <= qX) {
            f32x4 s[4];
            __builtin_amdgcn_s_setprio(1);
            #pragma unroll
            for (int g = 0; g < 4; ++g) {
                f32x4 acc = (f32x4){0.f, 0.f, 0.f, 0.f};
                #pragma unroll
                for (int f = 0; f < 4; ++f) {
                    bf16x8 kf = *(const bf16x8*)&Ks[(g * 16 + ln) * 128 + colK[f]];
                    acc = __builtin_amdgcn_mfma_f32_16x16x32_bf16(kf, qf[f], acc, 0, 0, 0);
                }
                s[g] = acc;
            }
            __builtin_amdgcn_s_setprio(0);
            if (kt == qX) {
                const int qrow = rX + ln;
                #pragma unroll
                for (int g = 0; g < 4; ++g)
                    #pragma unroll
                    for (int reg = 0; reg < 4; ++reg) {
                        const int key = k0 + g * 16 + quad * 4 + reg;
                        if (key > qrow) s[g][reg] = -1e30f;
                    }
            }
            float mt = s[0][0];
            #pragma unroll
            for (int g = 0; g < 4; ++g)
                #pragma unroll
                for (int reg = 0; reg < 4; ++reg)
                    mt = fmaxf(mt, s[g][reg]);
            mt = fmaxf(mt, __shfl_xor(mt, 16, 64));
            mt = fmaxf(mt, __shfl_xor(mt, 32, 64));
            const float mnew = fmaxf(mX, mt);
            // T13 defer-max: if max grew by <= 6 in exp2 domain (P <= 64),
            // keep old max and skip the O-rescale pass.
            const bool defer = __all((mnew - mX) * SC <= 6.0f);
            const float mref = defer ? mX : mnew;
            const float c1 = SC * mref;
            const float alpha = exp2f(__builtin_fmaf(SC, mX, -c1)); // ==1 deferred
            float ps = 0.f;
            #pragma unroll
            for (int g = 0; g < 4; ++g) {
                float p0 = exp2f(__builtin_fmaf(s[g][0], SC, -c1));
                float p1 = exp2f(__builtin_fmaf(s[g][1], SC, -c1));
                float p2 = exp2f(__builtin_fmaf(s[g][2], SC, -c1));
                float p3 = exp2f(__builtin_fmaf(s[g][3], SC, -c1));
                ps += (p0 + p1) + (p2 + p3);
                uint2 pk;
                pk.x = pkbf(p0, p1);
                pk.y = pkbf(p2, p3);
                const int sg = (2 * g + (quad >> 1)) ^ lnm;       // swizzled granule
                *(uint2*)&Ps[w][ln * 64 + sg * 8 + (quad & 1) * 4] = pk;
            }
            ps += __shfl_xor(ps, 16, 64);
            ps += __shfl_xor(ps, 32, 64);
            mX = mref;
            if (defer) {
                lX += ps;
            } else {
                lX = lX * alpha + ps;
                #pragma unroll
                for (int dg = 0; dg < 8; ++dg) {
                    Oa[dg][0] *= alpha; Oa[dg][1] *= alpha;
                    Oa[dg][2] *= alpha; Oa[dg][3] *= alpha;
                }
            }
            __asm volatile("s_waitcnt lgkmcnt(0)" ::: "memory");
            bf16x8 pf0 = *(const bf16x8*)&Ps[w][ln * 64 + colA];
            bf16x8 pf1 = *(const bf16x8*)&Ps[w][ln * 64 + colB];
            __builtin_amdgcn_s_setprio(1);
            #pragma unroll
            for (int dg = 0; dg < 8; ++dg) {
                bf16x8 vf0 = *(const bf16x8*)&Vt[(dg * 16 + ln) * 64 + colA];
                bf16x8 vf1 = *(const bf16x8*)&Vt[(dg * 16 + ln) * 64 + colB];
                Oa[dg] = __builtin_amdgcn_mfma_f32_16x16x32_bf16(vf0, pf0, Oa[dg], 0, 0, 0);
                Oa[dg] = __builtin_amdgcn_mfma_f32_16x16x32_bf16(vf1, pf1, Oa[dg], 0, 0, 0);
            }
            __builtin_amdgcn_s_setprio(0);
        }
    }

    {
        const float inv = 1.0f / lX;
        short* orow = o + ((size_t)(b * SEQ + rX + ln) * NH + h) * HD;
        #pragma unroll
        for (int dg = 0; dg < 8; ++dg) {
            uint2 ov;
            ov.x = pkbf(Oa[dg][0] * inv, Oa[dg][1] * inv);
            ov.y = pkbf(Oa[dg][2] * inv, Oa[dg][3] * inv);
            *(uint2*)(orow + dg * 16 + quad * 4) = ov;
        }
    }
}

// ---------------------------------------------------------------------------
extern "C" void kernel_launch(void* const* d_in, const int* in_sizes, int n_in,
                              void* d_out, int out_size, void* d_ws, size_t ws_size,
                              hipStream_t stream)
{
    const float* hs = (const float*)d_in[0];
    const float* Wq = (const float*)d_in[2];
    const float* Wk = (const float*)d_in[3];
    const float* Wv = (const float*)d_in[4];
    const float* Wo = (const float*)d_in[5];
    const float* qw = (const float*)d_in[6];
    const float* kw = (const float*)d_in[7];
    float* out = (float*)d_out;

    const size_t MEG = 1024 * 1024;
    short* hsb  = (short*)d_ws;          // 8M bf16: hs; later reused as attn-out
    short* wqkv = hsb + 8 * MEG;         // 6M bf16: Wq|Wk|Wv fused [3072][2048]
    short* wob  = wqkv + 6 * MEG;        // 4M bf16: Wo
    short* qkvb = wob + 4 * MEG;         // 12M bf16: fused qkv [4096][3072]
    float2* rtab = (float2*)(qkvb + 12 * MEG);   // 1M: rope cos/sin [SEQ][64]
    short* vT   = (short*)d_out;         // 4M bf16 in d_out (dead until O-proj)

    dim3 blk(256);

    cast_all<<<dim3(18944), blk, 0, stream>>>(hs, Wq, Wk, Wv, Wo, hsb, wqkv, wob, rtab);

    // fused QKV projection: grid 768 blocks (24 n-tiles x 32 m-tiles, n-fast)
    gemm_nt_mfma<true><<<dim3(768), blk, 0, stream>>>(
        hsb, wqkv, qkvb, QKV, 2048, 24, 768);

    // fused RMSNorm+RoPE (20480 blocks) + V-transpose (2048 blocks)
    norm_rope_tv<<<dim3(NR_BLOCKS + 2048), blk, 0, stream>>>(qkvb, qw, kw, vT, rtab);

    flash_attn_mfma<<<dim3(512), dim3(512), 0, stream>>>(qkvb, vT, hsb);

    // output projection: grid 512 blocks (16 n-tiles x 32 m-tiles, n-fast)
    gemm_nt_mfma<false><<<dim3(512), blk, 0, stream>>>(
        hsb, wob, out, 2048, 2048, 16, 512);
}

// Round 14
// 313.149 us; speedup vs baseline: 1.0483x; 1.0483x over previous
//
#include <hip/hip_runtime.h>
#include <hip/hip_bf16.h>
#include <math.h>

#define NH 16
#define NKV 4
#define HD 128
#define SEQ 2048
#define BATCH 2
#define EPSF 1e-6f
#define QKV 3072      // fused projection width: 2048 q | 512 k | 512 v

typedef __attribute__((ext_vector_type(8))) short bf16x8;
typedef __attribute__((ext_vector_type(4))) short short4v;
typedef __attribute__((ext_vector_type(4))) float f32x4;

__device__ __forceinline__ short f2bf(float x) {
    unsigned u = __float_as_uint(x);
    u += 0x7fffu + ((u >> 16) & 1u);      // round-to-nearest-even
    return (short)(u >> 16);
}
__device__ __forceinline__ float bf2f(short x) {
    return __uint_as_float((unsigned)(unsigned short)x << 16);
}
// packed f32x2 -> bf16x2 (v_cvt_pk_bf16_f32), RNE
__device__ __forceinline__ unsigned pkbf(float a, float b) {
    __hip_bfloat162 h = __float22bfloat162_rn(float2{a, b});
    unsigned r; __builtin_memcpy(&r, &h, 4); return r;
}

// async global->LDS, 16B per lane; LDS dest = wave-uniform base + lane*16
__device__ __forceinline__ void gll16(const short* g, short* l) {
    __builtin_amdgcn_global_load_lds(
        (const __attribute__((address_space(1))) unsigned*)g,
        (__attribute__((address_space(3))) unsigned*)l, 16, 0, 0);
}

// ---------------------------------------------------------------------------
// Fused fp32->bf16 casts + RoPE cos/sin table build.
// blocks [0,8192): hs, [8192,12288): Wq, [12288,13312): Wk,
// [13312,14336): Wv, [14336,18432): Wo, [18432,18944): rope table.
// ---------------------------------------------------------------------------
__global__ __launch_bounds__(256)
void cast_all(const float* __restrict__ hs, const float* __restrict__ Wq,
              const float* __restrict__ Wk, const float* __restrict__ Wv,
              const float* __restrict__ Wo, short* __restrict__ hsb,
              short* __restrict__ wqkv, short* __restrict__ wob,
              float2* __restrict__ rtab)
{
    const size_t MEG = 1024 * 1024;
    const int id = blockIdx.x;
    if (id >= 18432) {
        // rope table: rtab[s*64+j] = {cos, sin} of s * 10000^(-j/64)
        const int idx = (id - 18432) * 256 + threadIdx.x;   // 0..131071
        const int s = idx >> 6, j = idx & 63;
        const float inv_freq = exp2f(-(float)j * (13.287712379549449f / 64.0f));
        const float ang = (float)s * inv_freq;
        float sn, c;
        __sincosf(ang, &sn, &c);
        rtab[idx] = float2{c, sn};
        return;
    }
    const float* s;
    short* d;
    size_t off;
    if (id < 8192)       { s = hs; d = hsb;            off = (size_t)id * 1024; }
    else if (id < 12288) { s = Wq; d = wqkv;           off = (size_t)(id - 8192) * 1024; }
    else if (id < 13312) { s = Wk; d = wqkv + 4 * MEG; off = (size_t)(id - 12288) * 1024; }
    else if (id < 14336) { s = Wv; d = wqkv + 5 * MEG; off = (size_t)(id - 13312) * 1024; }
    else                 { s = Wo; d = wob;            off = (size_t)(id - 14336) * 1024; }
    const size_t i = off + threadIdx.x * 4;
    float4 v = *(const float4*)(s + i);
    short4v o;
    o.x = f2bf(v.x); o.y = f2bf(v.y); o.z = f2bf(v.z); o.w = f2bf(v.w);
    *(short4v*)(d + i) = o;
}

// ---------------------------------------------------------------------------
// bf16 MFMA GEMM NT (measured-best config, FINAL): 128x128 tile, BK=64,
// XOR-swizzled LDS (gll16-compatible), XCD-aware remap (n-fast walk),
// 256 threads, LB(256,4). C[M,N] = A[M,K] @ B[N,K]^T, fp32 accum.
// Measured notes: n-fast beats m-fast (R11 +15us regression); 256x256
// 8-phase loses at these grid sizes (R3/R4 +35us).
// ---------------------------------------------------------------------------
template<bool OUT_BF16>
__global__ __launch_bounds__(256, 4)
void gemm_nt_mfma(const short* __restrict__ A, const short* __restrict__ B,
                  void* __restrict__ Cv, int N, int K, int gridX, int total)
{
    __shared__ short As[128 * 64];
    __shared__ short Bs[128 * 64];

    const int tid = threadIdx.x;
    const int w = tid >> 6, lane = tid & 63;
    const int quad = lane >> 4, ln = lane & 15;
    const int mw = (w >> 1) * 64, nw = (w & 1) * 64;

    // XCD-aware remap: XCD (id&7) walks a contiguous chunk of tiles
    const int id = blockIdx.x;
    const int t = (id & 7) * (total >> 3) + (id >> 3);
    const int n0 = (t % gridX) * 128;
    const int m0 = (t / gridX) * 128;

    // staging: wave w, round r covers rows w*8 + 32r + (lane>>3),
    // lane fetches swizzled source granule ((lane&7) ^ (lane>>3))
    const int rr = lane >> 3;
    const int gsw = ((lane & 7) ^ rr) * 8;
    const short* Ag[4]; const short* Bg[4];
    short* Al[4]; short* Bl[4];
    #pragma unroll
    for (int r = 0; r < 4; ++r) {
        const int row = w * 8 + 32 * r + rr;
        Ag[r] = A + (size_t)(m0 + row) * K + gsw;
        Bg[r] = B + (size_t)(n0 + row) * K + gsw;
        Al[r] = &As[(w * 8 + 32 * r) * 64];
        Bl[r] = &Bs[(w * 8 + 32 * r) * 64];
    }

    // read column offsets (shorts) for substeps ks=0,1: ((ks*4+quad)^(ln&7))*8
    const int col0 = ((quad) ^ (ln & 7)) * 8;
    const int col1 = ((4 + quad) ^ (ln & 7)) * 8;

    f32x4 acc[4][4];
    #pragma unroll
    for (int i = 0; i < 4; ++i)
        #pragma unroll
        for (int j = 0; j < 4; ++j)
            acc[i][j] = (f32x4){0.f, 0.f, 0.f, 0.f};

    for (int k0 = 0; k0 < K; k0 += 64) {
        __syncthreads();
        #pragma unroll
        for (int r = 0; r < 4; ++r) {
            gll16(Ag[r] + k0, Al[r]);
            gll16(Bg[r] + k0, Bl[r]);
        }
        __syncthreads();   // drains vmcnt -> LDS populated

        #pragma unroll
        for (int ks = 0; ks < 2; ++ks) {
            const int col = ks ? col1 : col0;
            bf16x8 af[4], bfr[4];
            #pragma unroll
            for (int i = 0; i < 4; ++i)
                af[i] = *(const bf16x8*)&As[(mw + i * 16 + ln) * 64 + col];
            #pragma unroll
            for (int j = 0; j < 4; ++j)
                bfr[j] = *(const bf16x8*)&Bs[(nw + j * 16 + ln) * 64 + col];
            #pragma unroll
            for (int i = 0; i < 4; ++i)
                #pragma unroll
                for (int j = 0; j < 4; ++j)
                    acc[i][j] = __builtin_amdgcn_mfma_f32_16x16x32_bf16(
                        af[i], bfr[j], acc[i][j], 0, 0, 0);
        }
    }

    #pragma unroll
    for (int i = 0; i < 4; ++i) {
        #pragma unroll
        for (int reg = 0; reg < 4; ++reg) {
            const int row = m0 + mw + i * 16 + quad * 4 + reg;
            const size_t base = (size_t)row * N + n0 + nw;
            #pragma unroll
            for (int j = 0; j < 4; ++j) {
                if (OUT_BF16)
                    ((short*)Cv)[base + j * 16 + ln] = f2bf(acc[i][j][reg]);
                else
                    ((float*)Cv)[base + j * 16 + ln] = acc[i][j][reg];
            }
        }
    }
}

// ---------------------------------------------------------------------------
// Fused: RMSNorm+RoPE on q|k (blocks [0,20480)) AND V-transpose
// (blocks [20480,22528)). RoPE cos/sin from precomputed table.
// ---------------------------------------------------------------------------
#define NR_BLOCKS 20480    // (BATCH*SEQ*(NH+NKV))/4
__global__ __launch_bounds__(256)
void norm_rope_tv(short* __restrict__ qkv, const float* __restrict__ qw,
                  const float* __restrict__ kw, short* __restrict__ vT,
                  const float2* __restrict__ rtab)
{
    if (blockIdx.x < NR_BLOCKS) {
        // ---- RMSNorm + RoPE ----
        const int wave = threadIdx.x >> 6;
        const int lane = threadIdx.x & 63;
        const long vec = (long)blockIdx.x * 4 + wave;
        const long NQ = (long)BATCH * SEQ * NH;

        short* base;
        const float* w;
        int s;
        if (vec < NQ) {
            const long token = vec / NH;
            const int h = (int)(vec % NH);
            s = (int)(token % SEQ);
            base = qkv + token * QKV + h * HD;
            w = qw;
        } else {
            const long t = vec - NQ;
            const long token = t / NKV;
            const int kvh = (int)(t % NKV);
            s = (int)(token % SEQ);
            base = qkv + token * QKV + 2048 + kvh * HD;
            w = kw;
        }

        float x0 = bf2f(base[lane]);
        float x1 = bf2f(base[lane + 64]);
        float ss = x0 * x0 + x1 * x1;
        #pragma unroll
        for (int off = 32; off; off >>= 1) ss += __shfl_xor(ss, off, 64);
        const float r = rsqrtf(ss * (1.0f / HD) + EPSF);
        x0 = x0 * r * w[lane];
        x1 = x1 * r * w[lane + 64];

        const float2 cs = rtab[(size_t)s * 64 + lane];
        base[lane]      = f2bf(x0 * cs.x - x1 * cs.y);
        base[lane + 64] = f2bf(x1 * cs.x + x0 * cs.y);
    } else {
        // ---- V transpose: qkv[token][2560+kvh*128+d] -> vT[b][kvh][d][s] ----
        __shared__ short T[32][33];
        const int bx = blockIdx.x - NR_BLOCKS;
        const int st = bx & 63;
        const int dt = (bx >> 6) & 3;
        const int bk = bx >> 8;
        const int s0 = st * 32, d0 = dt * 32;
        const int tid = threadIdx.x;
        const long tok0 = (long)(bk >> 2) * SEQ + s0;
        const int kvh = bk & 3;

        const int rs = tid >> 3;
        const int rc = (tid & 7) * 4;
        short4v val = *(const short4v*)(qkv + (tok0 + rs) * QKV + 2560 + kvh * HD + d0 + rc);
        T[rc + 0][rs] = val.x; T[rc + 1][rs] = val.y;
        T[rc + 2][rs] = val.z; T[rc + 3][rs] = val.w;
        __syncthreads();

        const int wd = tid >> 3;
        const int wsc = (tid & 7) * 4;
        short4v ov;
        ov.x = T[wd][wsc + 0]; ov.y = T[wd][wsc + 1];
        ov.z = T[wd][wsc + 2]; ov.w = T[wd][wsc + 3];
        *(short4v*)(vT + ((size_t)bk * HD + d0 + wd) * SEQ + s0 + wsc) = ov;
    }
}

// ---------------------------------------------------------------------------
// Flash causal GQA attention v4 (measured-best config, FINAL): 8 waves,
// paired complementary (qa=pair, qb=31-pair) q-groups sharing K/V staging.
// bf16 MFMA, fp32 accum. T2 XOR swizzle on Ks/Vt/Ps, T5 setprio,
// T13 defer-max.
// ---------------------------------------------------------------------------
__global__ __launch_bounds__(512, 4)
void flash_attn_mfma(const short* __restrict__ qkv, const short* __restrict__ vT,
                     short* __restrict__ o)
{
    __shared__ short Ks[64 * 128];     // [key][d], 16 granules/row, XOR-swizzled
    __shared__ short Vt[128 * 64];     // [d][key], 8 granules/row, XOR-swizzled
    __shared__ short Ps[8][16 * 64];   // per-wave [q][key], XOR-swizzled

    const int tid = threadIdx.x;
    const int w = tid >> 6;            // 0..7
    const int lane = tid & 63;
    const int quad = lane >> 4;
    const int ln = lane & 15;
    const int lnm = ln & 7;
    const int side = w >> 2;           // 0 -> qa, 1 -> qb
    const int sw = w & 3;

    const int bx = blockIdx.x;
    const int pair = bx & 15;
    const int bh = bx >> 4;
    const int h = bh & 15;
    const int b = bh >> 4;
    const int kvh = h >> 2;
    const int qa = pair, qb = 31 - pair;
    const int qX = side ? qb : qa;
    const int rX = qX * 64 + sw * 16;

    const float SC = 0.08838834764831845f * 1.4426950408889634f; // 1/sqrt(HD)*log2e

    // swizzled read column offsets (shorts): logical granule ^ (row&7 == ln&7)
    int colK[4];
    #pragma unroll
    for (int f = 0; f < 4; ++f) {
        const int lg = f * 4 + quad;                    // logical granule 0..15
        colK[f] = ((lg & 8) | ((lg ^ lnm) & 7)) * 8;
    }
    const int colA = (quad ^ lnm) * 8;                  // logical granule quad
    const int colB = ((4 + quad) ^ lnm) * 8;            // logical granule 4+quad

    // Q -> B-frags (lane ln = q row rX+ln)
    bf16x8 qf[4];
    {
        const short* qrow = qkv + (size_t)(b * SEQ + rX + ln) * QKV + h * HD;
        #pragma unroll
        for (int f = 0; f < 4; ++f)
            qf[f] = *(const bf16x8*)(qrow + f * 32 + quad * 8);
    }

    f32x4 Oa[8];
    #pragma unroll
    for (int dg = 0; dg < 8; ++dg) Oa[dg] = (f32x4){0.f, 0.f, 0.f, 0.f};
    float mX = -1e30f, lX = 0.f;

    const short* kbase = qkv + (size_t)(b * SEQ) * QKV + 2048 + kvh * HD;
    const short* vbase = vT + (size_t)(b * NKV + kvh) * HD * SEQ;

    bf16x8 kp[2], vp[2];
    auto prefetch = [&](int k0) {
        #pragma unroll
        for (int i = 0; i < 2; ++i) {
            const int e = tid + i * 512;
            kp[i] = *(const bf16x8*)(kbase + (size_t)(k0 + (e >> 4)) * QKV + (e & 15) * 8);
            vp[i] = *(const bf16x8*)(vbase + (size_t)(e >> 3) * SEQ + k0 + (e & 7) * 8);
        }
    };
    prefetch(0);

    for (int kt = 0; kt <= qb; ++kt) {
        const int k0 = kt * 64;
        __syncthreads();
        #pragma unroll
        for (int i = 0; i < 2; ++i) {
            const int e = tid + i * 512;
            const int kr = e >> 4, kg = e & 15;
            *(bf16x8*)&Ks[kr * 128 + ((kg & 8) | ((kg ^ (kr & 7)) & 7)) * 8] = kp[i];
            const int vd = e >> 3, vg = e & 7;
            *(bf16x8*)&Vt[vd * 64 + ((vg ^ (vd & 7)) * 8)] = vp[i];
        }
        __syncthreads();
        if (kt < qb) prefetch(k0 + 64);

        if (kt <= qX) {
            f32x4 s[4];
            __builtin_amdgcn_s_setprio(1);
            #pragma unroll
            for (int g = 0; g < 4; ++g) {
                f32x4 acc = (f32x4){0.f, 0.f, 0.f, 0.f};
                #pragma unroll
                for (int f = 0; f < 4; ++f) {
                    bf16x8 kf = *(const bf16x8*)&Ks[(g * 16 + ln) * 128 + colK[f]];
                    acc = __builtin_amdgcn_mfma_f32_16x16x32_bf16(kf, qf[f], acc, 0, 0, 0);
                }
                s[g] = acc;
            }
            __builtin_amdgcn_s_setprio(0);
            if (kt == qX) {
                const int qrow = rX + ln;
                #pragma unroll
                for (int g = 0; g < 4; ++g)
                    #pragma unroll
                    for (int reg = 0; reg < 4; ++reg) {
                        const int key = k0 + g * 16 + quad * 4 + reg;
                        if (key > qrow) s[g][reg] = -1e30f;
                    }
            }
            float mt = s[0][0];
            #pragma unroll
            for (int g = 0; g < 4; ++g)
                #pragma unroll
                for (int reg = 0; reg < 4; ++reg)
                    mt = fmaxf(mt, s[g][reg]);
            mt = fmaxf(mt, __shfl_xor(mt, 16, 64));
            mt = fmaxf(mt, __shfl_xor(mt, 32, 64));
            const float mnew = fmaxf(mX, mt);
            // T13 defer-max: if max grew by <= 6 in exp2 domain (P <= 64),
            // keep old max and skip the O-rescale pass.
            const bool defer = __all((mnew - mX) * SC <= 6.0f);
            const float mref = defer ? mX : mnew;
            const float c1 = SC * mref;
            const float alpha = exp2f(__builtin_fmaf(SC, mX, -c1)); // ==1 deferred
            float ps = 0.f;
            #pragma unroll
            for (int g = 0; g < 4; ++g) {
                float p0 = exp2f(__builtin_fmaf(s[g][0], SC, -c1));
                float p1 = exp2f(__builtin_fmaf(s[g][1], SC, -c1));
                float p2 = exp2f(__builtin_fmaf(s[g][2], SC, -c1));
                float p3 = exp2f(__builtin_fmaf(s[g][3], SC, -c1));
                ps += (p0 + p1) + (p2 + p3);
                uint2 pk;
                pk.x = pkbf(p0, p1);
                pk.y = pkbf(p2, p3);
                const int sg = (2 * g + (quad >> 1)) ^ lnm;       // swizzled granule
                *(uint2*)&Ps[w][ln * 64 + sg * 8 + (quad & 1) * 4] = pk;
            }
            ps += __shfl_xor(ps, 16, 64);
            ps += __shfl_xor(ps, 32, 64);
            mX = mref;
            if (defer) {
                lX += ps;
            } else {
                lX = lX * alpha + ps;
                #pragma unroll
                for (int dg = 0; dg < 8; ++dg) {
                    Oa[dg][0] *= alpha; Oa[dg][1] *= alpha;
                    Oa[dg][2] *= alpha; Oa[dg][3] *= alpha;
                }
            }
            __asm volatile("s_waitcnt lgkmcnt(0)" ::: "memory");
            bf16x8 pf0 = *(const bf16x8*)&Ps[w][ln * 64 + colA];
            bf16x8 pf1 = *(const bf16x8*)&Ps[w][ln * 64 + colB];
            __builtin_amdgcn_s_setprio(1);
            #pragma unroll
            for (int dg = 0; dg < 8; ++dg) {
                bf16x8 vf0 = *(const bf16x8*)&Vt[(dg * 16 + ln) * 64 + colA];
                bf16x8 vf1 = *(const bf16x8*)&Vt[(dg * 16 + ln) * 64 + colB];
                Oa[dg] = __builtin_amdgcn_mfma_f32_16x16x32_bf16(vf0, pf0, Oa[dg], 0, 0, 0);
                Oa[dg] = __builtin_amdgcn_mfma_f32_16x16x32_bf16(vf1, pf1, Oa[dg], 0, 0, 0);
            }
            __builtin_amdgcn_s_setprio(0);
        }
    }

    {
        const float inv = 1.0f / lX;
        short* orow = o + ((size_t)(b * SEQ + rX + ln) * NH + h) * HD;
        #pragma unroll
        for (int dg = 0; dg < 8; ++dg) {
            uint2 ov;
            ov.x = pkbf(Oa[dg][0] * inv, Oa[dg][1] * inv);
            ov.y = pkbf(Oa[dg][2] * inv, Oa[dg][3] * inv);
            *(uint2*)(orow + dg * 16 + quad * 4) = ov;
        }
    }
}

// ---------------------------------------------------------------------------
extern "C" void kernel_launch(void* const* d_in, const int* in_sizes, int n_in,
                              void* d_out, int out_size, void* d_ws, size_t ws_size,
                              hipStream_t stream)
{
    const float* hs = (const float*)d_in[0];
    const float* Wq = (const float*)d_in[2];
    const float* Wk = (const float*)d_in[3];
    const float* Wv = (const float*)d_in[4];
    const float* Wo = (const float*)d_in[5];
    const float* qw = (const float*)d_in[6];
    const float* kw = (const float*)d_in[7];
    float* out = (float*)d_out;

    const size_t MEG = 1024 * 1024;
    short* hsb  = (short*)d_ws;          // 8M bf16: hs; later reused as attn-out
    short* wqkv = hsb + 8 * MEG;         // 6M bf16: Wq|Wk|Wv fused [3072][2048]
    short* wob  = wqkv + 6 * MEG;        // 4M bf16: Wo
    short* qkvb = wob + 4 * MEG;         // 12M bf16: fused qkv [4096][3072]
    float2* rtab = (float2*)(qkvb + 12 * MEG);   // 1M: rope cos/sin [SEQ][64]
    short* vT   = (short*)d_out;         // 4M bf16 in d_out (dead until O-proj)

    dim3 blk(256);

    cast_all<<<dim3(18944), blk, 0, stream>>>(hs, Wq, Wk, Wv, Wo, hsb, wqkv, wob, rtab);

    // fused QKV projection: grid 768 blocks (24 n-tiles x 32 m-tiles, n-fast)
    gemm_nt_mfma<true><<<dim3(768), blk, 0, stream>>>(
        hsb, wqkv, qkvb, QKV, 2048, 24, 768);

    // fused RMSNorm+RoPE (20480 blocks) + V-transpose (2048 blocks)
    norm_rope_tv<<<dim3(NR_BLOCKS + 2048), blk, 0, stream>>>(qkvb, qw, kw, vT, rtab);

    flash_attn_mfma<<<dim3(512), dim3(512), 0, stream>>>(qkvb, vT, hsb);

    // output projection: grid 512 blocks (16 n-tiles x 32 m-tiles, n-fast)
    gemm_nt_mfma<false><<<dim3(512), blk, 0, stream>>>(
        hsb, wob, out, 2048, 2048, 16, 512);
}